// Round 8
// baseline (349.188 us; speedup 1.0000x reference)
//
#include <hip/hip_runtime.h>

typedef __attribute__((ext_vector_type(8))) short short8;
typedef __attribute__((ext_vector_type(4))) float f32x4;

#define NB    32
#define CINC  64
#define COUTC 64
#define HWDIM 128
#define NPIX  16384
#define XT_H  130
#define ADIMC 64
#define WTOT  36864   // COUT*CIN*9

#define ROWB  8320    // bytes per (plane,row): 130 px * 32 c * 2 B
#define ROWP  9216    // LDS row pitch: 9 chunks of 1 KiB (pad absorbs the 8320B tail)

__device__ inline unsigned short f2bf(float f) {
    unsigned int u = __float_as_uint(f);
    u += 0x7FFF + ((u >> 16) & 1);   // RNE
    return (unsigned short)(u >> 16);
}

// async global->LDS, 16B per lane; LDS dest = wave-uniform base + lane*16
__device__ inline void gload_lds16(const void* g, void* l) {
    __builtin_amdgcn_global_load_lds(
        (__attribute__((address_space(1))) void*)g,
        (__attribute__((address_space(3))) void*)l, 16, 0, 0);
}

// ---------------------------------------------------------------------------
// prep: x [32,64,128,128] fp32 NCHW -> xt [32, kc=2, 130, 130, 32] bf16
//       (split-cin padded NHWC planes)
// R8: pool partials now accumulate DIRECTLY into pooled_raw[32][64] via
// atomicAdd (device scope), eliminating the 1 MB partial buffer and the
// entire mlp1 dispatch. 64 atomics/block, 128 adds per address total.
// grid (128 hrows, 32 b), 256 threads
// ---------------------------------------------------------------------------
__global__ __launch_bounds__(256) void prep_kernel(
        const float* __restrict__ x, float* __restrict__ pooled_raw,
        unsigned short* __restrict__ xt) {
    __shared__ float lds[CINC][128];
    const int b = blockIdx.y, hrow = blockIdx.x, t = threadIdx.x;

    // phase 1: coalesced float4 reads along w, swizzled transpose into LDS
    #pragma unroll
    for (int it = 0; it < 8; ++it) {
        const int c  = (t >> 5) + it * 8;          // c>>3 == it
        const int w4 = (t & 31) * 4;
        f32x4 v = *(const f32x4*)(x + (((size_t)b * CINC + c) * HWDIM + hrow) * HWDIM + w4);
        *(f32x4*)&lds[c][w4 ^ (it << 2)] = v;
        float s = v[0] + v[1] + v[2] + v[3];
        for (int off = 16; off > 0; off >>= 1) s += __shfl_down(s, off, 32);
        if ((t & 31) == 0) atomicAdd(&pooled_raw[b * CINC + c], s);
    }
    __syncthreads();

    // phase 2: write split-cin bf16 planes, 16B per lane
    for (int q = t; q < 1024; q += 256) {
        const int w = q >> 3, cg = (q & 7) * 8;
        const int xorc = (q & 7) << 2;
        short8 o;
        #pragma unroll
        for (int i = 0; i < 8; ++i) o[i] = (short)f2bf(lds[cg + i][w ^ xorc]);
        *(short8*)(xt + ((((size_t)b * 2 + (cg >> 5)) * XT_H + hrow + 1) * XT_H + (w + 1)) * 32
                      + (cg & 31)) = o;
    }

    // halo zeroing (both planes)
    if (hrow == 0) {
        for (int kc = 0; kc < 2; ++kc) {
            unsigned int* r0 = (unsigned int*)(xt + ((size_t)(b * 2 + kc) * XT_H) * XT_H * 32);
            for (int i = t; i < XT_H * 32 / 2; i += 256) r0[i] = 0u;
        }
    }
    if (hrow == HWDIM - 1) {
        for (int kc = 0; kc < 2; ++kc) {
            unsigned int* r129 = (unsigned int*)(xt + (((size_t)(b * 2 + kc) * XT_H) + 129) * XT_H * 32);
            for (int i = t; i < XT_H * 32 / 2; i += 256) r129[i] = 0u;
        }
    }
    if (t < 64) {
        const int kc = (t >> 4) & 1, wcol = (t >= 32) ? 129 : 0, i = t & 15;
        unsigned int* p = (unsigned int*)(xt + ((((size_t)(b * 2 + kc) * XT_H) + hrow + 1) * XT_H + wcol) * 32);
        p[i] = 0u;
    }
}

// ---------------------------------------------------------------------------
// adapt: prelude computes h = relu(pooled_raw/16384 @ w1 + b1) from the 8 KB
// atomic-pooled buffer (L2-hot, ~1 µs over 128 blocks) — replaces the mlp1
// kernel. Then the R1-exact body: a = tanh(h @ w2 + b2);
// adapted = base_w + scale*a in MFMA-fragment order [b][e][kc][mi][lane][8].
// ---------------------------------------------------------------------------
__global__ __launch_bounds__(320) void adapt_kernel(
        const float* __restrict__ pooled_raw, const float* __restrict__ w1,
        const float* __restrict__ b1, const float* __restrict__ w2,
        const float* __restrict__ b2, const float* __restrict__ base_w,
        const float* __restrict__ scale_p, unsigned short* __restrict__ adp) {
    __shared__ float pl[NB * CINC];         //  8 KB
    __shared__ float lh[NB * ADIMC];        //  8 KB
    __shared__ unsigned short lo[288 * 33]; // 19 KB
    const int t = threadIdx.x, blk = blockIdx.x;

    for (int i = t; i < NB * CINC; i += 320)
        pl[i] = pooled_raw[i] * (1.0f / NPIX);
    __syncthreads();

    for (int i = t; i < NB * ADIMC; i += 320) {
        const int b = i >> 6, j = i & 63;
        float acc = b1[j];
        for (int k = 0; k < CINC; ++k)
            acc = fmaf(pl[b * CINC + k], w1[k * ADIMC + j], acc);
        lh[i] = fmaxf(acc, 0.0f);
    }
    __syncthreads();

    const float sc = scale_p[0];

    if (t < 288) {
        const int j = blk * 288 + t;
        float acc[NB];
        #pragma unroll
        for (int b = 0; b < NB; ++b) acc[b] = 0.0f;
        for (int k = 0; k < ADIMC; ++k) {
            const float wv = w2[(size_t)k * WTOT + j];
            #pragma unroll
            for (int b = 0; b < NB; ++b) acc[b] = fmaf(lh[b * ADIMC + k], wv, acc[b]);
        }
        const float bw = base_w[j], bb = b2[j];
        #pragma unroll
        for (int b = 0; b < NB; ++b) {
            const float val = bw + sc * tanhf(acc[b] + bb);
            lo[t * 33 + b] = f2bf(val);
        }
    }
    __syncthreads();

    const int co = blk >> 1, kc = blk & 1;
    const int mi = co >> 4, lmv = co & 15;
    for (int o = t; o < 9216; o += 320) {
        const int bb = o / 288;
        const int rem = o - bb * 288;
        const int e = rem >> 5, ci = rem & 31;
        const int hi = ci >> 3, j8 = ci & 7;
        adp[(((((size_t)bb * 9 + e) * 2 + kc) * 4 + mi) * 64 + hi * 16 + lmv) * 8 + j8]
            = lo[(ci * 9 + e) * 33 + bb];
    }
}

// ---------------------------------------------------------------------------
// conv: R1-EXACT (measured best; frozen).
// 9 shifted GEMMs via mfma_f32_16x16x32_bf16, LDS-staged B operand,
// single-buffer 36.9 KB, (256,3), plain 2-D grid.
// Verdict log: A-prefetch null (R4), dbuf/2blk −12 (R2), no-LDS −12 (R5),
// T14 reg-stage −13 (R7), (256,4)+swizzle −54 (R3). Do not touch.
// ---------------------------------------------------------------------------
__global__ __launch_bounds__(256, 3) void conv_kernel(
        const unsigned short* __restrict__ xt, const unsigned short* __restrict__ adp,
        const float* __restrict__ base_b, float* __restrict__ out) {
    __shared__ __align__(1024) char smem[4 * ROWP];   // 36,864 B
    const int b = blockIdx.y, tile = blockIdx.x, t = threadIdx.x;
    const int wv = t >> 6, lane = t & 63, lm = lane & 15, lq = lane >> 4;
    const int hrow = tile * 2 + (wv >> 1);    // output row of this wave
    const int wc = (wv & 1) * 64;
    const int r0w = wv >> 1;

    f32x4 acc[4][4];
    #pragma unroll
    for (int mi = 0; mi < 4; ++mi)
        #pragma unroll
        for (int ni = 0; ni < 4; ++ni) acc[mi][ni] = (f32x4){0.f, 0.f, 0.f, 0.f};

    char* ldsrow = smem + wv * ROWP;

    for (int kc = 0; kc < 2; ++kc) {
        if (kc) __syncthreads();   // all waves done reading phase-0 LDS

        // stage: wave wv loads padded row (tile*2 + wv) of plane (b,kc).
        // LDS[y] = G[y ^ (((y>>7)&3)<<4)]  (involution, within-128B-line)
        {
            const char* srow = (const char*)xt
                + ((size_t)(b * 2 + kc) * XT_H + tile * 2 + wv) * ROWB;
            #pragma unroll
            for (int k = 0; k < 9; ++k) {
                const int y  = k * 1024 + (lane << 4);
                const int sw = y ^ (((y >> 7) & 3) << 4);
                gload_lds16(srow + sw, ldsrow + k * 1024);   // k=8 over-reads into
            }                                                 // next row: in-bounds pad
        }
        __syncthreads();

        const unsigned short* Akc = adp + (((size_t)b * 18 + kc) << 11);
        #pragma unroll
        for (int e = 0; e < 9; ++e) {
            const int ky = e / 3, kx = e % 3;
            const unsigned short* Ae = Akc + ((size_t)e << 12);
            short8 Af[4], Bf[4];
            #pragma unroll
            for (int mi = 0; mi < 4; ++mi)
                Af[mi] = *(const short8*)(Ae + ((mi * 64 + lane) << 3));
            const int rbase = (r0w + ky) * ROWP;
            #pragma unroll
            for (int ni = 0; ni < 4; ++ni) {
                const int xr = ((wc + lm + ni * 16 + kx) << 6) + (lq << 4);
                Bf[ni] = *(const short8*)(smem + rbase + (xr ^ (((xr >> 7) & 3) << 4)));
            }
            #pragma unroll
            for (int mi = 0; mi < 4; ++mi)
                #pragma unroll
                for (int ni = 0; ni < 4; ++ni)
                    acc[mi][ni] = __builtin_amdgcn_mfma_f32_16x16x32_bf16(
                        Af[mi], Bf[ni], acc[mi][ni], 0, 0, 0);
        }
    }

    // epilogue: D row = lq*4+r (cout offset), col = lm (pixel offset)
    const int pixbase = hrow * HWDIM + wc + lm;
    #pragma unroll
    for (int mi = 0; mi < 4; ++mi) {
        #pragma unroll
        for (int r = 0; r < 4; ++r) {
            const int cout = mi * 16 + lq * 4 + r;
            const float bb = base_b[cout];
            #pragma unroll
            for (int ni = 0; ni < 4; ++ni)
                out[((size_t)(b * COUTC + cout) << 14) + pixbase + ni * 16] = acc[mi][ni][r] + bb;
        }
    }
}

// ---------------------------------------------------------------------------
extern "C" void kernel_launch(void* const* d_in, const int* in_sizes, int n_in,
                              void* d_out, int out_size, void* d_ws, size_t ws_size,
                              hipStream_t stream) {
    const float* x      = (const float*)d_in[0];
    const float* base_w = (const float*)d_in[1];
    const float* base_b = (const float*)d_in[2];
    const float* w1     = (const float*)d_in[3];
    const float* b1     = (const float*)d_in[4];
    const float* w2     = (const float*)d_in[5];
    const float* b2     = (const float*)d_in[6];
    const float* scale  = (const float*)d_in[7];
    float* out = (float*)d_out;

    // workspace layout (unchanged byte offsets; pooled_raw in old partial slot)
    unsigned short* xt  = (unsigned short*)d_ws;                        // 69,222,400 B
    unsigned short* adp = (unsigned short*)((char*)d_ws + 69222400);    //  2,359,296 B
    float* pooled_raw   = (float*)((char*)d_ws + 71581696);             //      8,192 B

    hipMemsetAsync(pooled_raw, 0, NB * CINC * sizeof(float), stream);
    prep_kernel<<<dim3(HWDIM, NB), 256, 0, stream>>>(x, pooled_raw, xt);
    adapt_kernel<<<128, 320, 0, stream>>>(pooled_raw, w1, b1, w2, b2, base_w, scale, adp);
    conv_kernel<<<dim3(64, NB), 256, 0, stream>>>(xt, adp, base_b, out);
}

// Round 9
// 324.179 us; speedup vs baseline: 1.0771x; 1.0771x over previous
//
#include <hip/hip_runtime.h>

typedef __attribute__((ext_vector_type(8))) short short8;
typedef __attribute__((ext_vector_type(4))) float f32x4;

#define NB    32
#define CINC  64
#define COUTC 64
#define HWDIM 128
#define NPIX  16384
#define XT_H  130
#define ADIMC 64
#define WTOT  36864   // COUT*CIN*9

#define ROWB  8320    // bytes per (plane,row): 130 px * 32 c * 2 B
#define ROWP  9216    // LDS row pitch: 9 chunks of 1 KiB (pad absorbs the 8320B tail)

__device__ inline unsigned short f2bf(float f) {
    unsigned int u = __float_as_uint(f);
    u += 0x7FFF + ((u >> 16) & 1);   // RNE
    return (unsigned short)(u >> 16);
}

// async global->LDS, 16B per lane; LDS dest = wave-uniform base + lane*16
__device__ inline void gload_lds16(const void* g, void* l) {
    __builtin_amdgcn_global_load_lds(
        (__attribute__((address_space(1))) void*)g,
        (__attribute__((address_space(3))) void*)l, 16, 0, 0);
}

// ---------------------------------------------------------------------------
// prep: x [32,64,128,128] fp32 NCHW -> xt [32, kc=2, 130, 130, 32] bf16
//       + per-(b,hrow) pool partials (plain stores, no atomics — R8 lesson:
//       atomicAdd pooling cost ~20 µs in L2-RMW serialization).
// R9: one block per (hrow, b, kc) — grid (128, 64), 256 thr, 16 KB LDS.
// Rationale (R8 counters: 1.5 TB/s, VALU 7.6%, occ 35% = latency-bound):
// half the LDS -> 2x resident blocks -> 2x outstanding loads; half the work
// behind each barrier; phase-2 wave stores 1 KB contiguous.
// partial/xt values and layout bit-identical to R1.
// ---------------------------------------------------------------------------
__global__ __launch_bounds__(256) void prep_kernel(
        const float* __restrict__ x, float* __restrict__ partial,
        unsigned short* __restrict__ xt) {
    __shared__ float lds[32][128];   // 16 KB
    const int hrow = blockIdx.x, b = blockIdx.y >> 1, kc = blockIdx.y & 1;
    const int t = threadIdx.x;

    // phase 1: coalesced float4 reads along w, swizzled transpose into LDS.
    // c_loc = (t>>5) + it*8  ->  c_loc>>3 == it  (same xor family as R1)
    #pragma unroll
    for (int it = 0; it < 4; ++it) {
        const int cl = (t >> 5) + it * 8;
        const int w4 = (t & 31) * 4;
        f32x4 v = *(const f32x4*)(x +
            (((size_t)b * CINC + kc * 32 + cl) * HWDIM + hrow) * HWDIM + w4);
        *(f32x4*)&lds[cl][w4 ^ (it << 2)] = v;
        float s = v[0] + v[1] + v[2] + v[3];
        for (int off = 16; off > 0; off >>= 1) s += __shfl_down(s, off, 32);
        if ((t & 31) == 0)
            partial[((size_t)b * HWDIM + hrow) * CINC + kc * 32 + cl] = s;
    }
    __syncthreads();

    // phase 2: write this (b,kc) plane's row, 16B per lane, 1 KB/wave contig
    #pragma unroll
    for (int q = t; q < 512; q += 256) {
        const int w = q >> 2, cg = (q & 3) * 8;
        const int xorc = (q & 3) << 2;             // row group's it = q&3
        short8 o;
        #pragma unroll
        for (int i = 0; i < 8; ++i) o[i] = (short)f2bf(lds[cg + i][w ^ xorc]);
        *(short8*)(xt + ((((size_t)(b * 2 + kc)) * XT_H + hrow + 1) * XT_H + (w + 1)) * 32
                      + cg) = o;
    }

    // halo zeroing (this plane only)
    if (hrow == 0) {
        unsigned int* r0 = (unsigned int*)(xt + (size_t)(b * 2 + kc) * XT_H * XT_H * 32);
        for (int i = t; i < XT_H * 32 / 2; i += 256) r0[i] = 0u;
    }
    if (hrow == HWDIM - 1) {
        unsigned int* r129 = (unsigned int*)(xt + ((size_t)(b * 2 + kc) * XT_H + 129) * XT_H * 32);
        for (int i = t; i < XT_H * 32 / 2; i += 256) r129[i] = 0u;
    }
    if (t < 32) {
        const int wcol = (t < 16) ? 0 : 129, i = t & 15;
        unsigned int* p = (unsigned int*)(xt +
            (((size_t)(b * 2 + kc) * XT_H + hrow + 1) * XT_H + wcol) * 32);
        p[i] = 0u;
    }
}

// ---------------------------------------------------------------------------
// mlp1: reduce partials -> pooled; h = relu(pooled/16384 @ w1 + b1)  [32,64]
// [R1-exact — restored after R8's atomic experiment]
// ---------------------------------------------------------------------------
__global__ __launch_bounds__(256) void mlp1_kernel(
        const float* __restrict__ partial, const float* __restrict__ w1,
        const float* __restrict__ b1, float* __restrict__ hout) {
    __shared__ float red[256];
    __shared__ float pooled_s[CINC];
    const int b = blockIdx.x, t = threadIdx.x;
    const int c = t & 63, q = t >> 6;
    float s = 0.0f;
    for (int r = 0; r < 32; ++r)
        s += partial[((size_t)b * HWDIM + q * 32 + r) * CINC + c];
    red[t] = s;
    __syncthreads();
    if (t < 64)
        pooled_s[t] = (red[t] + red[t + 64] + red[t + 128] + red[t + 192]) * (1.0f / NPIX);
    __syncthreads();
    if (t < 64) {
        const int j = t;
        float acc = b1[j];
        for (int k = 0; k < CINC; ++k)
            acc = fmaf(pooled_s[k], w1[k * ADIMC + j], acc);
        hout[b * ADIMC + j] = fmaxf(acc, 0.0f);
    }
}

// ---------------------------------------------------------------------------
// adapt: a = tanh(h @ w2 + b2); adapted = base_w + scale*a
// output in MFMA-fragment order [b][e][kc][mi][lane][8]  [R1-exact]
// ---------------------------------------------------------------------------
__global__ __launch_bounds__(320) void adapt_kernel(
        const float* __restrict__ hin, const float* __restrict__ w2,
        const float* __restrict__ b2, const float* __restrict__ base_w,
        const float* __restrict__ scale_p, unsigned short* __restrict__ adp) {
    __shared__ float lh[NB * ADIMC];
    __shared__ unsigned short lo[288 * 33];
    const int t = threadIdx.x, blk = blockIdx.x;
    for (int i = t; i < NB * ADIMC; i += 320) lh[i] = hin[i];
    __syncthreads();
    const float sc = scale_p[0];

    if (t < 288) {
        const int j = blk * 288 + t;
        float acc[NB];
        #pragma unroll
        for (int b = 0; b < NB; ++b) acc[b] = 0.0f;
        for (int k = 0; k < ADIMC; ++k) {
            const float wv = w2[(size_t)k * WTOT + j];
            #pragma unroll
            for (int b = 0; b < NB; ++b) acc[b] = fmaf(lh[b * ADIMC + k], wv, acc[b]);
        }
        const float bw = base_w[j], bb = b2[j];
        #pragma unroll
        for (int b = 0; b < NB; ++b) {
            const float val = bw + sc * tanhf(acc[b] + bb);
            lo[t * 33 + b] = f2bf(val);
        }
    }
    __syncthreads();

    const int co = blk >> 1, kc = blk & 1;
    const int mi = co >> 4, lmv = co & 15;
    for (int o = t; o < 9216; o += 320) {
        const int bb = o / 288;
        const int rem = o - bb * 288;
        const int e = rem >> 5, ci = rem & 31;
        const int hi = ci >> 3, j8 = ci & 7;
        adp[(((((size_t)bb * 9 + e) * 2 + kc) * 4 + mi) * 64 + hi * 16 + lmv) * 8 + j8]
            = lo[(ci * 9 + e) * 33 + bb];
    }
}

// ---------------------------------------------------------------------------
// conv: R1-EXACT (measured best; frozen).
// 9 shifted GEMMs via mfma_f32_16x16x32_bf16, LDS-staged B operand,
// single-buffer 36.9 KB, (256,3), plain 2-D grid.
// Verdict log: A-prefetch null (R4), dbuf/2blk −12 (R2), no-LDS −12 (R5),
// T14 reg-stage −13 (R7), (256,4)+swizzle −54 (R3). Do not touch.
// ---------------------------------------------------------------------------
__global__ __launch_bounds__(256, 3) void conv_kernel(
        const unsigned short* __restrict__ xt, const unsigned short* __restrict__ adp,
        const float* __restrict__ base_b, float* __restrict__ out) {
    __shared__ __align__(1024) char smem[4 * ROWP];   // 36,864 B
    const int b = blockIdx.y, tile = blockIdx.x, t = threadIdx.x;
    const int wv = t >> 6, lane = t & 63, lm = lane & 15, lq = lane >> 4;
    const int hrow = tile * 2 + (wv >> 1);    // output row of this wave
    const int wc = (wv & 1) * 64;
    const int r0w = wv >> 1;

    f32x4 acc[4][4];
    #pragma unroll
    for (int mi = 0; mi < 4; ++mi)
        #pragma unroll
        for (int ni = 0; ni < 4; ++ni) acc[mi][ni] = (f32x4){0.f, 0.f, 0.f, 0.f};

    char* ldsrow = smem + wv * ROWP;

    for (int kc = 0; kc < 2; ++kc) {
        if (kc) __syncthreads();   // all waves done reading phase-0 LDS

        // stage: wave wv loads padded row (tile*2 + wv) of plane (b,kc).
        // LDS[y] = G[y ^ (((y>>7)&3)<<4)]  (involution, within-128B-line)
        {
            const char* srow = (const char*)xt
                + ((size_t)(b * 2 + kc) * XT_H + tile * 2 + wv) * ROWB;
            #pragma unroll
            for (int k = 0; k < 9; ++k) {
                const int y  = k * 1024 + (lane << 4);
                const int sw = y ^ (((y >> 7) & 3) << 4);
                gload_lds16(srow + sw, ldsrow + k * 1024);   // k=8 over-reads into
            }                                                 // next row: in-bounds pad
        }
        __syncthreads();

        const unsigned short* Akc = adp + (((size_t)b * 18 + kc) << 11);
        #pragma unroll
        for (int e = 0; e < 9; ++e) {
            const int ky = e / 3, kx = e % 3;
            const unsigned short* Ae = Akc + ((size_t)e << 12);
            short8 Af[4], Bf[4];
            #pragma unroll
            for (int mi = 0; mi < 4; ++mi)
                Af[mi] = *(const short8*)(Ae + ((mi * 64 + lane) << 3));
            const int rbase = (r0w + ky) * ROWP;
            #pragma unroll
            for (int ni = 0; ni < 4; ++ni) {
                const int xr = ((wc + lm + ni * 16 + kx) << 6) + (lq << 4);
                Bf[ni] = *(const short8*)(smem + rbase + (xr ^ (((xr >> 7) & 3) << 4)));
            }
            #pragma unroll
            for (int mi = 0; mi < 4; ++mi)
                #pragma unroll
                for (int ni = 0; ni < 4; ++ni)
                    acc[mi][ni] = __builtin_amdgcn_mfma_f32_16x16x32_bf16(
                        Af[mi], Bf[ni], acc[mi][ni], 0, 0, 0);
        }
    }

    // epilogue: D row = lq*4+r (cout offset), col = lm (pixel offset)
    const int pixbase = hrow * HWDIM + wc + lm;
    #pragma unroll
    for (int mi = 0; mi < 4; ++mi) {
        #pragma unroll
        for (int r = 0; r < 4; ++r) {
            const int cout = mi * 16 + lq * 4 + r;
            const float bb = base_b[cout];
            #pragma unroll
            for (int ni = 0; ni < 4; ++ni)
                out[((size_t)(b * COUTC + cout) << 14) + pixbase + ni * 16] = acc[mi][ni][r] + bb;
        }
    }
}

// ---------------------------------------------------------------------------
extern "C" void kernel_launch(void* const* d_in, const int* in_sizes, int n_in,
                              void* d_out, int out_size, void* d_ws, size_t ws_size,
                              hipStream_t stream) {
    const float* x      = (const float*)d_in[0];
    const float* base_w = (const float*)d_in[1];
    const float* base_b = (const float*)d_in[2];
    const float* w1     = (const float*)d_in[3];
    const float* b1     = (const float*)d_in[4];
    const float* w2     = (const float*)d_in[5];
    const float* b2     = (const float*)d_in[6];
    const float* scale  = (const float*)d_in[7];
    float* out = (float*)d_out;

    // workspace layout (unchanged byte offsets)
    unsigned short* xt  = (unsigned short*)d_ws;                        // 69,222,400 B
    unsigned short* adp = (unsigned short*)((char*)d_ws + 69222400);    //  2,359,296 B
    float* partial      = (float*)((char*)d_ws + 71581696);             //  1,048,576 B
    float* hbuf         = (float*)((char*)d_ws + 72630272);             //      8,192 B

    prep_kernel<<<dim3(HWDIM, NB * 2), 256, 0, stream>>>(x, partial, xt);
    mlp1_kernel<<<NB, 256, 0, stream>>>(partial, w1, b1, hbuf);
    adapt_kernel<<<128, 320, 0, stream>>>(hbuf, w2, b2, base_w, scale, adp);
    conv_kernel<<<dim3(64, NB), 256, 0, stream>>>(xt, adp, base_b, out);
}